// Round 1
// baseline (231.427 us; speedup 1.0000x reference)
//
#include <hip/hip_runtime.h>
#include <math.h>

#define BB 64
#define HH 8
#define Dh 64
#define EE 512
#define NBLK 32
#define BSZ 128
#define LL 4096

// ---------------- Kernel 1: fused QKV projections (GEMV) ----------------
// grid (B, 3), block 512. blockIdx.y: 0=q (scaled), 1=k, 2=v.
__global__ __launch_bounds__(512) void qkv_proj(
    const float* __restrict__ hidden,
    const float* __restrict__ q_w, const float* __restrict__ q_b,
    const float* __restrict__ k_w, const float* __restrict__ k_b,
    const float* __restrict__ v_w, const float* __restrict__ v_b,
    float* __restrict__ ws)
{
    const int b = blockIdx.x;
    const int proj = blockIdx.y;
    const int e = threadIdx.x;
    __shared__ float sh[EE];
    sh[e] = hidden[b * EE + e];
    __syncthreads();

    const float* w; const float* bias; float* out; float scale;
    if (proj == 0)      { w = q_w; bias = q_b; out = ws;             scale = 0.125f; } // D^-0.5
    else if (proj == 1) { w = k_w; bias = k_b; out = ws + BB * EE;   scale = 1.0f; }
    else                { w = v_w; bias = v_b; out = ws + 2*BB*EE;   scale = 1.0f; }

    const float4* wr = (const float4*)(w + (size_t)e * EE);
    const float4* h4 = (const float4*)sh;
    float acc = bias[e];
    #pragma unroll 8
    for (int i = 0; i < EE/4; ++i) {
        float4 a = wr[i]; float4 x = h4[i];
        acc += a.x*x.x + a.y*x.y + a.z*x.z + a.w*x.w;
    }
    out[b * EE + e] = acc * scale;
}

// ---------------- Kernel 2: paged attention per (b,h) ----------------
// grid (B*H), block 512 = 8 waves. 16-lane groups own rows (4 dims/lane).
__global__ __launch_bounds__(512) void attn(
    const float* __restrict__ ws,
    const float* __restrict__ kcache, const float* __restrict__ vcache,
    const float* __restrict__ mask,
    const int* __restrict__ cpos_p,
    const int* __restrict__ btab,
    float* __restrict__ ctx)
{
    const int bh = blockIdx.x;           // 0..511
    const int b  = bh >> 3;              // / H
    const int tid = threadIdx.x;         // 0..511
    const int grp = tid >> 4;            // 0..31
    const int l16 = tid & 15;
    const int wave = tid >> 6;
    const int lane = tid & 63;

    __shared__ float  s_scores[LL];      // 16 KB
    __shared__ float  s_q[Dh];
    __shared__ int    s_bt[NBLK];
    __shared__ float  s_red[8];
    __shared__ float  s_b;
    __shared__ float4 s_vp[8][16];

    const float* qv   = ws;
    const float* knew = ws + BB * EE;
    const float* vnew = ws + 2 * BB * EE;

    if (tid < Dh)   s_q[tid]  = qv[(size_t)bh * Dh + tid];
    if (tid < NBLK) s_bt[tid] = btab[b * NBLK + tid];
    const int cpos = *cpos_p;
    __syncthreads();

    const float4 q4 = ((const float4*)s_q)[l16];
    const size_t base = (size_t)bh * NBLK * BSZ * Dh;
    const float4* knew4 = (const float4*)(knew + (size_t)bh * Dh);
    const float4* vnew4 = (const float4*)(vnew + (size_t)bh * Dh);

    // ---- Phase 1: scores = q . K_gathered ----
    #pragma unroll 4
    for (int step = 0; step < LL/32; ++step) {
        const int row = step * 32 + grp;
        const int nb = row >> 7, j = row & (BSZ - 1);
        const float4* kr = (const float4*)(kcache + base + ((size_t)s_bt[nb] * BSZ + j) * Dh);
        if (row == cpos) kr = knew4;
        float4 kv = kr[l16];
        float p = q4.x*kv.x + q4.y*kv.y + q4.z*kv.z + q4.w*kv.w;
        p += __shfl_xor(p, 1); p += __shfl_xor(p, 2);
        p += __shfl_xor(p, 4); p += __shfl_xor(p, 8);
        if (l16 == 0) s_scores[row] = p;
    }
    __syncthreads();

    // ---- Phase 2: softmax over L (with additive mask) ----
    float loc[8];
    float m = -3.4e38f;
    const float* mrow = mask + (size_t)b * LL;
    #pragma unroll
    for (int i = 0; i < 8; ++i) {
        const int idx = tid + 512 * i;
        loc[i] = s_scores[idx] + mrow[idx];
        m = fmaxf(m, loc[i]);
    }
    #pragma unroll
    for (int o = 1; o < 64; o <<= 1) m = fmaxf(m, __shfl_xor(m, o));
    if (lane == 0) s_red[wave] = m;
    __syncthreads();
    if (tid == 0) {
        float mm = s_red[0];
        #pragma unroll
        for (int i = 1; i < 8; ++i) mm = fmaxf(mm, s_red[i]);
        s_b = mm;
    }
    __syncthreads();
    m = s_b;

    float ssum = 0.f;
    #pragma unroll
    for (int i = 0; i < 8; ++i) { loc[i] = expf(loc[i] - m); ssum += loc[i]; }
    #pragma unroll
    for (int o = 1; o < 64; o <<= 1) ssum += __shfl_xor(ssum, o);
    __syncthreads();                       // s_red / s_b reuse guard
    if (lane == 0) s_red[wave] = ssum;
    __syncthreads();
    if (tid == 0) {
        float s = 0.f;
        #pragma unroll
        for (int i = 0; i < 8; ++i) s += s_red[i];
        s_b = 1.0f / s;
    }
    __syncthreads();
    const float inv = s_b;
    #pragma unroll
    for (int i = 0; i < 8; ++i) s_scores[tid + 512 * i] = loc[i] * inv;
    __syncthreads();

    // ---- Phase 3: ctx = attn . V_gathered ----
    float4 acc = make_float4(0.f, 0.f, 0.f, 0.f);
    #pragma unroll 4
    for (int step = 0; step < LL/32; ++step) {
        const int row = step * 32 + grp;
        const int nb = row >> 7, j = row & (BSZ - 1);
        const float4* vr = (const float4*)(vcache + base + ((size_t)s_bt[nb] * BSZ + j) * Dh);
        if (row == cpos) vr = vnew4;
        float4 vv = vr[l16];
        const float w = s_scores[row];
        acc.x += w * vv.x; acc.y += w * vv.y; acc.z += w * vv.z; acc.w += w * vv.w;
    }
    // reduce the 4 groups within each wave (xor 16, 32 keep l16 fixed)
    #pragma unroll
    for (int o = 16; o < 64; o <<= 1) {
        acc.x += __shfl_xor(acc.x, o);
        acc.y += __shfl_xor(acc.y, o);
        acc.z += __shfl_xor(acc.z, o);
        acc.w += __shfl_xor(acc.w, o);
    }
    if (lane < 16) s_vp[wave][l16] = acc;
    __syncthreads();
    if (tid < 16) {
        float4 t = s_vp[0][tid];
        #pragma unroll
        for (int w = 1; w < 8; ++w) {
            float4 u = s_vp[w][tid];
            t.x += u.x; t.y += u.y; t.z += u.z; t.w += u.w;
        }
        ((float4*)(ctx + (size_t)bh * Dh))[tid] = t;
    }
}

// ---------------- Kernel 3: output projection (GEMV) ----------------
__global__ __launch_bounds__(512) void out_proj(
    const float* __restrict__ ctx,
    const float* __restrict__ o_w, const float* __restrict__ o_b,
    float* __restrict__ out)
{
    const int b = blockIdx.x;
    const int e = threadIdx.x;
    __shared__ float sh[EE];
    sh[e] = ctx[b * EE + e];
    __syncthreads();
    const float4* wr = (const float4*)(o_w + (size_t)e * EE);
    const float4* h4 = (const float4*)sh;
    float acc = o_b[e];
    #pragma unroll 8
    for (int i = 0; i < EE/4; ++i) {
        float4 a = wr[i]; float4 x = h4[i];
        acc += a.x*x.x + a.y*x.y + a.z*x.z + a.w*x.w;
    }
    out[b * EE + e] = acc;
}

extern "C" void kernel_launch(void* const* d_in, const int* in_sizes, int n_in,
                              void* d_out, int out_size, void* d_ws, size_t ws_size,
                              hipStream_t stream)
{
    const float* hidden = (const float*)d_in[0];
    const float* q_w = (const float*)d_in[1];
    const float* q_b = (const float*)d_in[2];
    const float* k_w = (const float*)d_in[3];
    const float* k_b = (const float*)d_in[4];
    const float* v_w = (const float*)d_in[5];
    const float* v_b = (const float*)d_in[6];
    const float* o_w = (const float*)d_in[7];
    const float* o_b = (const float*)d_in[8];
    const float* kcache = (const float*)d_in[9];
    const float* vcache = (const float*)d_in[10];
    const float* mask = (const float*)d_in[11];
    const int* cpos = (const int*)d_in[12];
    const int* btab = (const int*)d_in[13];

    float* ws  = (float*)d_ws;            // [q | k_new | v_new | ctx], 4*B*E floats
    float* ctx = ws + 3 * BB * EE;

    qkv_proj<<<dim3(BB, 3), 512, 0, stream>>>(hidden, q_w, q_b, k_w, k_b, v_w, v_b, ws);
    attn<<<dim3(BB * HH), 512, 0, stream>>>(ws, kcache, vcache, mask, cpos, btab, ctx);
    out_proj<<<dim3(BB), 512, 0, stream>>>(ctx, o_w, o_b, (float*)d_out);
}

// Round 4
// 191.065 us; speedup vs baseline: 1.2112x; 1.2112x over previous
//
#include <hip/hip_runtime.h>
#include <math.h>

#define BB 64
#define HH 8
#define Dh 64
#define EE 512
#define NBLK 32
#define BSZ 128
#define LL 4096
#define BG 4       // batches per projection block
#define RC 128     // weight rows per chunk (256 KB/block from L2)

typedef float f4 __attribute__((ext_vector_type(4)));

// ---------------- Kernel 1: QKV projections, chunked GEMV ----------------
// grid (BB/BG, 3, EE/RC) = (16,3,4), block 512.
// thread: r = tid&127 (output row in chunk), l4 = tid>>7 (dot quarter).
// Wave = 64 rows at the same quarter -> LDS hidden reads are wave-uniform
// (pure broadcast); per-block weight traffic = 128 rows x 2KB = 256 KB.
__global__ __launch_bounds__(512) void qkv_proj(
    const float* __restrict__ hidden,
    const float* __restrict__ q_w, const float* __restrict__ q_b,
    const float* __restrict__ k_w, const float* __restrict__ k_b,
    const float* __restrict__ v_w, const float* __restrict__ v_b,
    float* __restrict__ ws)
{
    const int bg = blockIdx.x, proj = blockIdx.y, chunk = blockIdx.z;
    const int tid = threadIdx.x;
    const int r  = tid & (RC - 1);
    const int l4 = tid >> 7;

    __shared__ float sh[BG][EE];
    __shared__ float sp[4][BG][RC];

    for (int i = tid; i < BG * EE; i += 512)
        sh[i >> 9][i & (EE - 1)] = hidden[(bg * BG + (i >> 9)) * EE + (i & (EE - 1))];
    __syncthreads();

    const float* w; const float* bias; float* out; float scale;
    if (proj == 0)      { w = q_w; bias = q_b; out = ws;             scale = 0.125f; } // D^-0.5
    else if (proj == 1) { w = k_w; bias = k_b; out = ws + BB * EE;   scale = 1.0f; }
    else                { w = v_w; bias = v_b; out = ws + 2*BB*EE;   scale = 1.0f; }

    const int e = chunk * RC + r;
    const float4* wr = (const float4*)(w + (size_t)e * EE + l4 * 128);
    float acc[BG] = {0.f, 0.f, 0.f, 0.f};
    #pragma unroll 8
    for (int i = 0; i < 32; ++i) {
        const float4 a = wr[i];
        #pragma unroll
        for (int b = 0; b < BG; ++b) {
            const float4 x = ((const float4*)sh[b])[l4 * 32 + i];
            acc[b] += a.x*x.x + a.y*x.y + a.z*x.z + a.w*x.w;
        }
    }
    #pragma unroll
    for (int b = 0; b < BG; ++b) sp[l4][b][r] = acc[b];
    __syncthreads();

    const int b2 = tid >> 7, r2 = tid & (RC - 1);
    const int e2 = chunk * RC + r2;
    const float v = sp[0][b2][r2] + sp[1][b2][r2] + sp[2][b2][r2] + sp[3][b2][r2];
    out[(bg * BG + b2) * EE + e2] = (v + bias[e2]) * scale;
}

// ---------------- Kernel 2: single-pass flash-decode per (b,h) ----------------
// grid (B*H), block 512 = 8 waves. 16-lane groups own rows (4 dims/lane);
// online softmax, K+V in one nontemporal stream. Block-table lookup hoisted
// per 128-row physical block.
__global__ __launch_bounds__(512) void attn(
    const float* __restrict__ ws,
    const float* __restrict__ kcache, const float* __restrict__ vcache,
    const float* __restrict__ mask,
    const int* __restrict__ cpos_p,
    const int* __restrict__ btab,
    float* __restrict__ ctx)
{
    const int bh = blockIdx.x;           // 0..511
    const int b  = bh >> 3;              // / H
    const int tid = threadIdx.x;         // 0..511
    const int grp = tid >> 4;            // 0..31
    const int l16 = tid & 15;

    __shared__ float  s_q[Dh];
    __shared__ int    s_bt[NBLK];
    __shared__ float  s_m[32];
    __shared__ float  s_s[32];
    __shared__ float4 s_acc[32][16];

    const float* qv   = ws;
    const float* knew = ws + BB * EE;
    const float* vnew = ws + 2 * BB * EE;

    if (tid < Dh)   s_q[tid]  = qv[(size_t)bh * Dh + tid];
    if (tid < NBLK) s_bt[tid] = btab[b * NBLK + tid];
    const int cpos = *cpos_p;
    __syncthreads();

    const float4 q4 = ((const float4*)s_q)[l16];
    const size_t base = (size_t)bh * NBLK * BSZ * Dh;
    const f4* knew4 = (const f4*)(knew + (size_t)bh * Dh);
    const f4* vnew4 = (const f4*)(vnew + (size_t)bh * Dh);
    const float* mrow = mask + (size_t)b * LL;

    float m = -3.4e38f, s = 0.f;
    float4 acc = make_float4(0.f, 0.f, 0.f, 0.f);

    #pragma unroll 2
    for (int c = 0; c < NBLK; ++c) {
        const size_t pb = base + (size_t)s_bt[c] * (BSZ * Dh);
        #pragma unroll
        for (int s4 = 0; s4 < 4; ++s4) {
            const int rl  = s4 * 32 + grp;       // row within physical block
            const int row = c * BSZ + rl;        // logical row
            const f4* kr = (const f4*)(kcache + pb + (size_t)rl * Dh);
            const f4* vr = (const f4*)(vcache + pb + (size_t)rl * Dh);
            if (row == cpos) { kr = knew4; vr = vnew4; }
            const f4 kv = __builtin_nontemporal_load(kr + l16);
            const f4 vv = __builtin_nontemporal_load(vr + l16);

            float p = q4.x*kv.x + q4.y*kv.y + q4.z*kv.z + q4.w*kv.w;
            p += __shfl_xor(p, 1); p += __shfl_xor(p, 2);
            p += __shfl_xor(p, 4); p += __shfl_xor(p, 8);
            p += mrow[row];                      // additive mask (broadcast)

            const float mn = fmaxf(m, p);
            const float cr = __expf(m - mn);     // -inf -> 0 on first iter
            const float wt = __expf(p - mn);
            s = s * cr + wt;
            acc.x = acc.x * cr + wt * vv.x;
            acc.y = acc.y * cr + wt * vv.y;
            acc.z = acc.z * cr + wt * vv.z;
            acc.w = acc.w * cr + wt * vv.w;
            m = mn;
        }
    }

    // ---- merge 32 groups: log-sum-exp combine ----
    if (l16 == 0) { s_m[grp] = m; s_s[grp] = s; }
    s_acc[grp][l16] = acc;
    __syncthreads();

    if (tid < 32) {
        const float mg = s_m[tid];
        float M = mg;
        #pragma unroll
        for (int o = 1; o < 32; o <<= 1) M = fmaxf(M, __shfl_xor(M, o));
        const float c = __expf(mg - M);
        float st = s_s[tid] * c;
        #pragma unroll
        for (int o = 1; o < 32; o <<= 1) st += __shfl_xor(st, o);
        s_m[tid] = c;                            // reuse as per-group scale
        if (tid == 0) s_s[0] = 1.0f / st;
    }
    __syncthreads();

    if (tid < 16) {
        const float inv = s_s[0];
        float4 t = make_float4(0.f, 0.f, 0.f, 0.f);
        #pragma unroll
        for (int g = 0; g < 32; ++g) {
            const float c = s_m[g];
            const float4 u = s_acc[g][tid];
            t.x += c * u.x; t.y += c * u.y; t.z += c * u.z; t.w += c * u.w;
        }
        t.x *= inv; t.y *= inv; t.z *= inv; t.w *= inv;
        ((float4*)(ctx + (size_t)bh * Dh))[tid] = t;
    }
}

// ---------------- Kernel 3: output projection, chunked GEMV ----------------
// grid (BB/BG, EE/RC) = (16,4), block 512. Same structure as qkv_proj.
__global__ __launch_bounds__(512) void out_proj(
    const float* __restrict__ ctx,
    const float* __restrict__ o_w, const float* __restrict__ o_b,
    float* __restrict__ out)
{
    const int bg = blockIdx.x, chunk = blockIdx.y;
    const int tid = threadIdx.x;
    const int r  = tid & (RC - 1);
    const int l4 = tid >> 7;

    __shared__ float sh[BG][EE];
    __shared__ float sp[4][BG][RC];

    for (int i = tid; i < BG * EE; i += 512)
        sh[i >> 9][i & (EE - 1)] = ctx[(bg * BG + (i >> 9)) * EE + (i & (EE - 1))];
    __syncthreads();

    const int e = chunk * RC + r;
    const float4* wr = (const float4*)(o_w + (size_t)e * EE + l4 * 128);
    float acc[BG] = {0.f, 0.f, 0.f, 0.f};
    #pragma unroll 8
    for (int i = 0; i < 32; ++i) {
        const float4 a = wr[i];
        #pragma unroll
        for (int b = 0; b < BG; ++b) {
            const float4 x = ((const float4*)sh[b])[l4 * 32 + i];
            acc[b] += a.x*x.x + a.y*x.y + a.z*x.z + a.w*x.w;
        }
    }
    #pragma unroll
    for (int b = 0; b < BG; ++b) sp[l4][b][r] = acc[b];
    __syncthreads();

    const int b2 = tid >> 7, r2 = tid & (RC - 1);
    const int e2 = chunk * RC + r2;
    const float v = sp[0][b2][r2] + sp[1][b2][r2] + sp[2][b2][r2] + sp[3][b2][r2];
    out[(bg * BG + b2) * EE + e2] = v + o_b[e2];
}

extern "C" void kernel_launch(void* const* d_in, const int* in_sizes, int n_in,
                              void* d_out, int out_size, void* d_ws, size_t ws_size,
                              hipStream_t stream)
{
    const float* hidden = (const float*)d_in[0];
    const float* q_w = (const float*)d_in[1];
    const float* q_b = (const float*)d_in[2];
    const float* k_w = (const float*)d_in[3];
    const float* k_b = (const float*)d_in[4];
    const float* v_w = (const float*)d_in[5];
    const float* v_b = (const float*)d_in[6];
    const float* o_w = (const float*)d_in[7];
    const float* o_b = (const float*)d_in[8];
    const float* kcache = (const float*)d_in[9];
    const float* vcache = (const float*)d_in[10];
    const float* mask = (const float*)d_in[11];
    const int* cpos = (const int*)d_in[12];
    const int* btab = (const int*)d_in[13];

    float* ws  = (float*)d_ws;            // [q | k_new | v_new | ctx], 4*B*E floats
    float* ctx = ws + 3 * BB * EE;

    qkv_proj<<<dim3(BB/BG, 3, EE/RC), 512, 0, stream>>>(hidden, q_w, q_b, k_w, k_b, v_w, v_b, ws);
    attn<<<dim3(BB * HH), 512, 0, stream>>>(ws, kcache, vcache, mask, cpos, btab, ctx);
    out_proj<<<dim3(BB/BG, EE/RC), 512, 0, stream>>>(ctx, o_w, o_b, (float*)d_out);
}